// Round 1
// baseline (316.122 us; speedup 1.0000x reference)
//
#include <hip/hip_runtime.h>

#define B_   16384
#define I_   35
#define E_   256
#define C_   64
#define K_   8960   // I_*4*C_
#define F_   140    // 4*I_
#define ROWS 32

// ws layout (floats):
//   Apack: [I_][E_][8] = 71680 floats
//     slot 0=Ad, 1=Ac, 2=Ar, 3=Aemb(t=0), 4=Aemb(t=1), 5=Aemb(t=2), 6=Aemb(t=3), 7=pad(unused)
//   Bp:    [3][E_] bias partials at float offset 71680
#define WS_BP 71680

__global__ __launch_bounds__(64) void precompute_kernel(
    const float* __restrict__ Wd, const float* __restrict__ bd,
    const float* __restrict__ Wc, const float* __restrict__ bc,
    const float* __restrict__ Wr, const float* __restrict__ br,
    const float* __restrict__ emb, const float* __restrict__ Wf,
    float* __restrict__ ws)
{
    const int e    = blockIdx.x;     // 0..255
    const int g    = blockIdx.y;     // 0..6  (0=Wd,1=Wc,2=Wr,3..6 = emb t=0..3)
    const int lane = threadIdx.x;    // 0..63
    const int gsel = (g < 3) ? g : 3;
    const float* wfrow = Wf + (size_t)e * K_ + gsel * C_ + lane;

    if (g < 3) {
        const float* wtab = (g == 0) ? Wd : (g == 1) ? Wc : Wr;
        const float* btab = (g == 0) ? bd : (g == 1) ? bc : br;
        float bacc = 0.f;
        for (int k = 0; k < I_; ++k) {
            float wf = wfrow[k * E_];            // Wf[e, k*256 + g*64 + lane]
            float p  = wtab[k * C_ + lane] * wf;
            bacc    += btab[k * C_ + lane] * wf;
            #pragma unroll
            for (int m = 1; m < 64; m <<= 1) p += __shfl_xor(p, m, 64);
            if (lane == 0) ws[(size_t)(k * E_ + e) * 8 + g] = p;
        }
        #pragma unroll
        for (int m = 1; m < 64; m <<= 1) bacc += __shfl_xor(bacc, m, 64);
        if (lane == 0) ws[WS_BP + g * E_ + e] = bacc;
    } else {
        const int t = g - 3;                      // emb slot, identity-mapped
        for (int k = 0; k < I_; ++k) {
            float wf = wfrow[k * E_];            // Wf[e, k*256 + 192 + lane]
            float p  = emb[(size_t)(k * 4 + t) * C_ + lane] * wf;
            #pragma unroll
            for (int m = 1; m < 64; m <<= 1) p += __shfl_xor(p, m, 64);
            if (lane == 0) ws[(size_t)(k * E_ + e) * 8 + g] = p;
        }
    }
}

__global__ __launch_bounds__(256) void main_kernel(
    const float* __restrict__ metadata,
    const float* __restrict__ bf,
    const float* __restrict__ gamma, const float* __restrict__ beta,
    const float* __restrict__ ws,
    float* __restrict__ out)
{
    const int e  = threadIdx.x;                  // output channel
    const int b0 = blockIdx.x * ROWS;
    // thread-invariant base pointer -> compiler emits scalar (s_load) reads
    const float* mrow  = metadata + (size_t)b0 * F_;
    const int*   mbits = (const int*)mrow;

    float base = bf[e] + ws[WS_BP + 0 * E_ + e]
                       + ws[WS_BP + 1 * E_ + e]
                       + ws[WS_BP + 2 * E_ + e];
    float acc[ROWS];
    #pragma unroll
    for (int r = 0; r < ROWS; ++r) acc[r] = base;

    #pragma unroll 1
    for (int i = 0; i < I_; ++i) {
        const float4* ap = (const float4*)(ws + (size_t)(i * E_ + e) * 8);
        const float4 a0 = ap[0];   // Ad, Ac, Ar, Aemb(t0)
        const float4 a1 = ap[1];   // Aemb(t1), Aemb(t2), Aemb(t3), pad
        #pragma unroll
        for (int r = 0; r < ROWS; ++r) {
            const float d  = mrow[r * F_ + 0 * I_ + i];   // uniform -> SGPR
            const float c  = mrow[r * F_ + 1 * I_ + i];
            const float rl = mrow[r * F_ + 2 * I_ + i];
            const int   ub = mbits[r * F_ + 3 * I_ + i];  // raw rt bits
            // raw in {0.0, 1.0, -1.0, -2.0} -> t in {0, 1, 2, 3}
            const float em = (ub == 0)          ? a0.w
                           : (ub == 0x3F800000) ? a1.x
                           : (ub == 0xBF800000) ? a1.y
                           :                      a1.z;
            acc[r] += d * a0.x + c * a0.y + rl * a0.z + em;
        }
    }

    // fused LayerNorm + ReLU; block-wide (256-ch) moments per row
    __shared__ float redS[ROWS][4];
    __shared__ float redQ[ROWS][4];
    const int w = e >> 6, lane = e & 63;
    #pragma unroll
    for (int r = 0; r < ROWS; ++r) {
        float s = acc[r], q = s * s;
        #pragma unroll
        for (int m = 1; m < 64; m <<= 1) {
            s += __shfl_xor(s, m, 64);
            q += __shfl_xor(q, m, 64);
        }
        if (lane == 0) { redS[r][w] = s; redQ[r][w] = q; }
    }
    __syncthreads();
    const float g_ = gamma[e], bt = beta[e];
    #pragma unroll
    for (int r = 0; r < ROWS; ++r) {
        const float S  = redS[r][0] + redS[r][1] + redS[r][2] + redS[r][3];
        const float Q  = redQ[r][0] + redQ[r][1] + redQ[r][2] + redQ[r][3];
        const float mu = S * (1.f / E_);
        const float var = Q * (1.f / E_) - mu * mu;
        const float sc  = rsqrtf(var + 1e-5f);
        const float v   = (acc[r] - mu) * sc * g_ + bt;
        out[(size_t)(b0 + r) * E_ + e] = fmaxf(v, 0.f);
    }
}

extern "C" void kernel_launch(void* const* d_in, const int* in_sizes, int n_in,
                              void* d_out, int out_size, void* d_ws, size_t ws_size,
                              hipStream_t stream) {
    const float* metadata = (const float*)d_in[0];
    const float* Wd  = (const float*)d_in[1];
    const float* bd  = (const float*)d_in[2];
    const float* Wc  = (const float*)d_in[3];
    const float* bc  = (const float*)d_in[4];
    const float* Wr  = (const float*)d_in[5];
    const float* br  = (const float*)d_in[6];
    const float* emb = (const float*)d_in[7];
    const float* Wf  = (const float*)d_in[8];
    const float* bf  = (const float*)d_in[9];
    const float* gamma = (const float*)d_in[10];
    const float* beta  = (const float*)d_in[11];
    float* ws = (float*)d_ws;

    dim3 pg(E_, 7);
    precompute_kernel<<<pg, 64, 0, stream>>>(Wd, bd, Wc, bc, Wr, br, emb, Wf, ws);
    main_kernel<<<B_ / ROWS, E_, 0, stream>>>(metadata, bf, gamma, beta, ws,
                                              (float*)d_out);
}

// Round 2
// 145.849 us; speedup vs baseline: 2.1675x; 2.1675x over previous
//
#include <hip/hip_runtime.h>

#define B_   16384
#define I_   35
#define E_   256
#define C_   64
#define K_   8960   // I_*4*C_
#define F_   140    // 4*I_
#define ROWS 16

// ws layout (floats):
//   Arec:   [I_][E_][8]  = 71680   record: Ad, Ac, Ar, k0, k1, k2, k3, pad
//   EmbRaw: [I_][E_][4]  = 35840   raw emb dot-products (t=0..3)
//   BiasP:  [3][E_]      = 768     bias partials (atomicAdd, memset to 0 first)
#define WS_EMBRAW 71680
#define WS_BIASP  107520
#define ICHUNK 5
#define IPER   7   // 35 = 5*7

__global__ __launch_bounds__(64) void precompute_kernel(
    const float* __restrict__ Wd, const float* __restrict__ bd,
    const float* __restrict__ Wc, const float* __restrict__ bc,
    const float* __restrict__ Wr, const float* __restrict__ br,
    const float* __restrict__ emb, const float* __restrict__ Wf,
    float* __restrict__ ws)
{
    const int e    = blockIdx.x;     // 0..255
    const int g    = blockIdx.y;     // 0..6  (0=Wd,1=Wc,2=Wr,3..6 = emb t)
    const int ic   = blockIdx.z;     // 0..4  (i chunk)
    const int lane = threadIdx.x;    // 0..63
    const int gsel = (g < 3) ? g : 3;
    const float* wfbase = Wf + (size_t)e * K_ + gsel * C_ + lane;

    if (g < 3) {
        const float* wtab = (g == 0) ? Wd : (g == 1) ? Wc : Wr;
        const float* btab = (g == 0) ? bd : (g == 1) ? bc : br;
        float bacc = 0.f;
        #pragma unroll
        for (int ii = 0; ii < IPER; ++ii) {
            const int i = ic * IPER + ii;
            const float wf = wfbase[i * E_];
            float p = wtab[i * C_ + lane] * wf;
            bacc   += btab[i * C_ + lane] * wf;
            #pragma unroll
            for (int m = 1; m < 64; m <<= 1) p += __shfl_xor(p, m, 64);
            if (lane == 0) ws[(size_t)(i * E_ + e) * 8 + g] = p;
        }
        #pragma unroll
        for (int m = 1; m < 64; m <<= 1) bacc += __shfl_xor(bacc, m, 64);
        if (lane == 0) atomicAdd(&ws[WS_BIASP + g * E_ + e], bacc);
    } else {
        const int t = g - 3;
        #pragma unroll
        for (int ii = 0; ii < IPER; ++ii) {
            const int i = ic * IPER + ii;
            const float wf = wfbase[i * E_];
            float p = emb[(size_t)(i * 4 + t) * C_ + lane] * wf;
            #pragma unroll
            for (int m = 1; m < 64; m <<= 1) p += __shfl_xor(p, m, 64);
            if (lane == 0) ws[WS_EMBRAW + (size_t)(i * E_ + e) * 4 + t] = p;
        }
    }
}

// Solve the 4-point Vandermonde (x in {0,1,-1,-2}) -> cubic coeffs k0..k3.
__global__ __launch_bounds__(128) void finalize_kernel(float* __restrict__ ws)
{
    const int gid = blockIdx.x * 128 + threadIdx.x;   // 0..8959 = i*256+e
    const float* er = ws + WS_EMBRAW + (size_t)gid * 4;
    const float v0 = er[0], v1 = er[1], v2 = er[2], v3 = er[3];
    const float a = v1 - v0, b = v2 - v0, c = v3 - v0;
    const float k2 = 0.5f * (a + b);
    const float s  = 0.5f * (a - b);          // k1 + k3
    const float u  = 0.5f * (4.f * k2 - c);   // k1 + 4*k3
    const float k3 = (u - s) * (1.f / 3.f);
    const float k1 = s - k3;
    float* rec = ws + (size_t)gid * 8;
    rec[3] = v0; rec[4] = k1; rec[5] = k2; rec[6] = k3; rec[7] = 0.f;
}

__global__ __launch_bounds__(256) void main_kernel(
    const float* __restrict__ metadata,
    const float* __restrict__ bf,
    const float* __restrict__ gamma, const float* __restrict__ beta,
    const float* __restrict__ ws,
    float* __restrict__ out)
{
    // ldsT[i][r][4] with per-i stride 68 floats (=272 B, 16B-aligned, bank-skewed)
    __shared__ float ldsT[I_ * 68];
    __shared__ float redS[ROWS][4];
    __shared__ float redQ[ROWS][4];

    const int e  = threadIdx.x;
    const int b0 = blockIdx.x * ROWS;

    // stage metadata transposed into LDS: (d, c, rl, rt_raw) contiguous per (i,r)
    for (int idx = e; idx < F_ * ROWS; idx += 256) {
        const int r  = idx & (ROWS - 1);
        const int kk = idx >> 4;                      // 0..139
        const float v = metadata[(size_t)(b0 + r) * F_ + kk];
        const int j = kk / 35;
        const int i = kk - 35 * j;
        ldsT[i * 68 + r * 4 + j] = v;
    }

    const float base = bf[e] + ws[WS_BIASP + e]
                             + ws[WS_BIASP + E_ + e]
                             + ws[WS_BIASP + 2 * E_ + e];
    float acc[ROWS];
    #pragma unroll
    for (int r = 0; r < ROWS; ++r) acc[r] = base;
    __syncthreads();

    const float4* Arec4 = (const float4*)ws;
    #pragma unroll 2
    for (int i = 0; i < I_; ++i) {
        const float4 a0 = Arec4[(size_t)(i * E_ + e) * 2];      // Ad,Ac,Ar,k0
        const float4 a1 = Arec4[(size_t)(i * E_ + e) * 2 + 1];  // k1,k2,k3,pad
        #pragma unroll
        for (int r = 0; r < ROWS; ++r) {
            const float4 m = *(const float4*)&ldsT[i * 68 + r * 4];
            // emb(x) = ((k3*x + k2)*x + k1)*x + k0, x = raw rt float
            float h = fmaf(a1.z, m.w, a1.y);
            h = fmaf(h, m.w, a1.x);
            h = fmaf(h, m.w, a0.w);
            float t = acc[r];
            t = fmaf(a0.x, m.x, t);
            t = fmaf(a0.y, m.y, t);
            t = fmaf(a0.z, m.z, t);
            acc[r] = t + h;
        }
    }

    // fused LayerNorm + ReLU
    const int w = e >> 6, lane = e & 63;
    #pragma unroll
    for (int r = 0; r < ROWS; ++r) {
        float s = acc[r], q = s * s;
        #pragma unroll
        for (int m = 1; m < 64; m <<= 1) {
            s += __shfl_xor(s, m, 64);
            q += __shfl_xor(q, m, 64);
        }
        if (lane == 0) { redS[r][w] = s; redQ[r][w] = q; }
    }
    __syncthreads();
    const float g_ = gamma[e], bt = beta[e];
    #pragma unroll
    for (int r = 0; r < ROWS; ++r) {
        const float S  = redS[r][0] + redS[r][1] + redS[r][2] + redS[r][3];
        const float Q  = redQ[r][0] + redQ[r][1] + redQ[r][2] + redQ[r][3];
        const float mu = S * (1.f / E_);
        const float var = Q * (1.f / E_) - mu * mu;
        const float sc  = rsqrtf(var + 1e-5f);
        const float v   = (acc[r] - mu) * sc * g_ + bt;
        out[(size_t)(b0 + r) * E_ + e] = fmaxf(v, 0.f);
    }
}

extern "C" void kernel_launch(void* const* d_in, const int* in_sizes, int n_in,
                              void* d_out, int out_size, void* d_ws, size_t ws_size,
                              hipStream_t stream) {
    const float* metadata = (const float*)d_in[0];
    const float* Wd  = (const float*)d_in[1];
    const float* bd  = (const float*)d_in[2];
    const float* Wc  = (const float*)d_in[3];
    const float* bc  = (const float*)d_in[4];
    const float* Wr  = (const float*)d_in[5];
    const float* br  = (const float*)d_in[6];
    const float* emb = (const float*)d_in[7];
    const float* Wf  = (const float*)d_in[8];
    const float* bf  = (const float*)d_in[9];
    const float* gamma = (const float*)d_in[10];
    const float* beta  = (const float*)d_in[11];
    float* ws = (float*)d_ws;

    hipMemsetAsync(ws + WS_BIASP, 0, 3 * E_ * sizeof(float), stream);
    dim3 pg(E_, 7, ICHUNK);
    precompute_kernel<<<pg, 64, 0, stream>>>(Wd, bd, Wc, bc, Wr, br, emb, Wf, ws);
    finalize_kernel<<<(I_ * E_) / 128, 128, 0, stream>>>(ws);
    main_kernel<<<B_ / ROWS, E_, 0, stream>>>(metadata, bf, gamma, beta, ws,
                                              (float*)d_out);
}

// Round 3
// 123.396 us; speedup vs baseline: 2.5619x; 1.1820x over previous
//
#include <hip/hip_runtime.h>

#define B_    16384
#define I_    35
#define ISLOT 36
#define E_    256
#define KP    288          // 8*ISLOT, K-dim padded (multiple of 32)
#define F_    140          // 4*I_
#define MROWS 32
#define NBLK  (B_ / MROWS) // 512
#define LROW  296          // feat LDS row stride in ushorts (592 B -> 2-way banks only)

typedef short bf16x8 __attribute__((ext_vector_type(8)));  // 8 bf16 = 4 VGPRs
typedef float f32x4  __attribute__((ext_vector_type(4)));  // MFMA C/D

__device__ __forceinline__ unsigned short f2bf(float f) {
    unsigned int u = __float_as_uint(f);
    u += 0x7FFFu + ((u >> 16) & 1u);               // RNE
    return (unsigned short)(u >> 16);
}

// One block per output channel e. Computes the 245 length-64 dot products,
// cubic (Vandermonde) solve for the embedding select, packs the K=288 bf16
// coefficient row AcombT[e][k], and folds all constants into base[e].
__global__ __launch_bounds__(256) void precompute_kernel(
    const float* __restrict__ Wd, const float* __restrict__ bd,
    const float* __restrict__ Wc, const float* __restrict__ bc,
    const float* __restrict__ Wr, const float* __restrict__ br,
    const float* __restrict__ emb, const float* __restrict__ Wf,
    const float* __restrict__ bf,
    unsigned short* __restrict__ At, float* __restrict__ base)
{
    __shared__ float wfs[8960];
    __shared__ float dots[7][40];
    __shared__ float bds[3][40];
    const int e = blockIdx.x, t = threadIdx.x;

    const float4* src = (const float4*)(Wf + (size_t)e * 8960);
    float4* dst = (float4*)wfs;
    for (int idx = t; idx < 2240; idx += 256) dst[idx] = src[idx];
    __syncthreads();

    if (t < 245) {
        const int g = t / 35, i = t - 35 * g;
        const int gsel = (g < 3) ? g : 3;
        const float* wf = wfs + i * 256 + gsel * 64;
        const float* tab = (g == 0) ? (Wd + i * 64)
                         : (g == 1) ? (Wc + i * 64)
                         : (g == 2) ? (Wr + i * 64)
                         : (emb + ((size_t)i * 4 + (g - 3)) * 64);
        const float* btab = (g == 0) ? (bd + i * 64)
                          : (g == 1) ? (bc + i * 64) : (br + i * 64);
        float dot = 0.f, bdot = 0.f;
        for (int cc = 0; cc < 64; ++cc) {
            const int c = (cc + t) & 63;           // rotate start: LDS bank-spread
            const float wv = wf[c];
            dot = fmaf(tab[c], wv, dot);
            if (g < 3) bdot = fmaf(btab[c], wv, bdot);
        }
        dots[g][i] = dot;
        if (g < 3) bds[g][i] = bdot;
    }
    __syncthreads();

    if (t < ISLOT) {
        union { unsigned short h[8]; int4 v; } p;
        if (t < I_) {
            const float v0 = dots[3][t], v1 = dots[4][t], v2 = dots[5][t], v3 = dots[6][t];
            const float a = v1 - v0, b = v2 - v0, c = v3 - v0;
            const float k2 = 0.5f * (a + b);
            const float s  = 0.5f * (a - b);           // k1 + k3
            const float u  = 0.5f * (4.f * k2 - c);    // k1 + 4*k3
            const float k3 = (u - s) * (1.f / 3.f);
            const float k1 = s - k3;
            p.h[0] = f2bf(dots[0][t]); p.h[1] = f2bf(dots[1][t]); p.h[2] = f2bf(dots[2][t]);
            p.h[3] = f2bf(k1);         p.h[4] = f2bf(k2);         p.h[5] = f2bf(k3);
            p.h[6] = 0; p.h[7] = 0;
        } else {
            p.v = make_int4(0, 0, 0, 0);               // pad slot i=35
        }
        *(int4*)(At + (size_t)e * KP + t * 8) = p.v;
    }
    if (t < 64) {                                      // base[e] = bf + bias dots + sum k0
        float part = (t < I_) ? (bds[0][t] + bds[1][t] + bds[2][t] + dots[3][t]) : 0.f;
        #pragma unroll
        for (int mm = 1; mm < 64; mm <<= 1) part += __shfl_xor(part, mm, 64);
        if (t == 0) base[e] = bf[e] + part;
    }
}

// out(16384 x 256) = feat(16384 x 288) @ AcombT^T via 16x16x32 bf16 MFMA,
// fused bias + LayerNorm + ReLU. Block = 32 rows x all 256 channels, 4 waves.
__global__ __launch_bounds__(256) void main_kernel(
    const float* __restrict__ metadata,
    const unsigned short* __restrict__ At,
    const float* __restrict__ base,
    const float* __restrict__ gamma, const float* __restrict__ beta,
    float* __restrict__ out)
{
    __shared__ unsigned short feat[MROWS * LROW];
    __shared__ float redS[4][MROWS];
    __shared__ float redQ[4][MROWS];

    const int t  = threadIdx.x;
    const int b0 = blockIdx.x * MROWS;

    // Build bf16 feature rows [d,c,rl,x,x^2,x^3,0,0] per (row, i) directly from global.
    for (int cell = t; cell < MROWS * ISLOT; cell += 256) {
        const int r = cell / ISLOT, i = cell - r * ISLOT;
        union { unsigned short h[8]; int4 v; } p;
        if (i < I_) {
            const float* mp = metadata + (size_t)(b0 + r) * F_ + i;
            const float d = mp[0], c = mp[I_], rl = mp[2 * I_], x = mp[3 * I_];
            const float x2 = x * x, x3 = x2 * x;
            p.h[0] = f2bf(d);  p.h[1] = f2bf(c);  p.h[2] = f2bf(rl);
            p.h[3] = f2bf(x);  p.h[4] = f2bf(x2); p.h[5] = f2bf(x3);
            p.h[6] = 0; p.h[7] = 0;
        } else {
            p.v = make_int4(0, 0, 0, 0);
        }
        *(int4*)(feat + r * LROW + i * 8) = p.v;
    }
    __syncthreads();

    const int lane = t & 63, w = t >> 6;
    const int nlo = lane & 15, q = lane >> 4;

    f32x4 acc[2][4];
    #pragma unroll
    for (int mt = 0; mt < 2; ++mt)
        #pragma unroll
        for (int nn = 0; nn < 4; ++nn) acc[mt][nn] = (f32x4){0.f, 0.f, 0.f, 0.f};

    // A-frag: lane holds feat[m = nlo][k = q*8 + j]; B-frag: At[e = nlo][k = q*8 + j]
    const unsigned short* ga = feat + nlo * LROW + q * 8;
    const unsigned short* gb = At + ((size_t)(w * 64 + nlo)) * KP + q * 8;

    #pragma unroll 3
    for (int ks = 0; ks < KP / 32; ++ks) {
        const bf16x8 a0 = *(const bf16x8*)(ga + ks * 32);
        const bf16x8 a1 = *(const bf16x8*)(ga + 16 * LROW + ks * 32);
        #pragma unroll
        for (int nn = 0; nn < 4; ++nn) {
            const bf16x8 b = *(const bf16x8*)(gb + (size_t)nn * 16 * KP + ks * 32);
            acc[0][nn] = __builtin_amdgcn_mfma_f32_16x16x32_bf16(a0, b, acc[0][nn], 0, 0, 0);
            acc[1][nn] = __builtin_amdgcn_mfma_f32_16x16x32_bf16(a1, b, acc[1][nn], 0, 0, 0);
        }
    }

    float baseN[4], gmN[4], btN[4];
    #pragma unroll
    for (int nn = 0; nn < 4; ++nn) {
        const int e = w * 64 + nn * 16 + nlo;
        baseN[nn] = base[e]; gmN[nn] = gamma[e]; btN[nn] = beta[e];
    }

    // Per-row moments: C/D layout row = q*4+reg (+16*mt), col = nlo (+16*nn).
    #pragma unroll
    for (int mt = 0; mt < 2; ++mt) {
        #pragma unroll
        for (int reg = 0; reg < 4; ++reg) {
            float s = 0.f, qq = 0.f;
            #pragma unroll
            for (int nn = 0; nn < 4; ++nn) {
                const float v = acc[mt][nn][reg] + baseN[nn];
                acc[mt][nn][reg] = v;
                s += v; qq += v * v;
            }
            #pragma unroll
            for (int mm = 1; mm < 16; mm <<= 1) {   // reduce over the 16 e-lanes
                s  += __shfl_xor(s, mm, 64);
                qq += __shfl_xor(qq, mm, 64);
            }
            if (nlo == 0) {
                const int row = mt * 16 + q * 4 + reg;
                redS[w][row] = s; redQ[w][row] = qq;
            }
        }
    }
    __syncthreads();

    #pragma unroll
    for (int mt = 0; mt < 2; ++mt) {
        #pragma unroll
        for (int reg = 0; reg < 4; ++reg) {
            const int row = mt * 16 + q * 4 + reg;
            const float S = redS[0][row] + redS[1][row] + redS[2][row] + redS[3][row];
            const float Q = redQ[0][row] + redQ[1][row] + redQ[2][row] + redQ[3][row];
            const float mu   = S * (1.f / E_);
            const float var  = Q * (1.f / E_) - mu * mu;
            const float rstd = rsqrtf(var + 1e-5f);
            float* orow = out + (size_t)(b0 + row) * E_ + w * 64 + nlo;
            #pragma unroll
            for (int nn = 0; nn < 4; ++nn) {
                const float v = (acc[mt][nn][reg] - mu) * rstd * gmN[nn] + btN[nn];
                orow[nn * 16] = fmaxf(v, 0.f);
            }
        }
    }
}

extern "C" void kernel_launch(void* const* d_in, const int* in_sizes, int n_in,
                              void* d_out, int out_size, void* d_ws, size_t ws_size,
                              hipStream_t stream) {
    const float* metadata = (const float*)d_in[0];
    const float* Wd  = (const float*)d_in[1];
    const float* bd  = (const float*)d_in[2];
    const float* Wc  = (const float*)d_in[3];
    const float* bc  = (const float*)d_in[4];
    const float* Wr  = (const float*)d_in[5];
    const float* br  = (const float*)d_in[6];
    const float* emb = (const float*)d_in[7];
    const float* Wf  = (const float*)d_in[8];
    const float* bf  = (const float*)d_in[9];
    const float* gamma = (const float*)d_in[10];
    const float* beta  = (const float*)d_in[11];

    unsigned short* At = (unsigned short*)d_ws;                    // 256*288*2 = 147456 B
    float* basep = (float*)((char*)d_ws + (size_t)E_ * KP * 2);    // 1 KB

    precompute_kernel<<<E_, 256, 0, stream>>>(Wd, bd, Wc, bc, Wr, br, emb, Wf, bf,
                                              At, basep);
    main_kernel<<<NBLK, 256, 0, stream>>>(metadata, At, basep, gamma, beta,
                                          (float*)d_out);
}

// Round 4
// 120.713 us; speedup vs baseline: 2.6188x; 1.0222x over previous
//
#include <hip/hip_runtime.h>

#define B_    16384
#define I_    35
#define ISLOT 36
#define E_    256
#define KP    288          // 8*ISLOT, K-dim padded (multiple of 32)
#define F_    140          // 4*I_
#define MROWS 32
#define NBLK  (B_ / MROWS) // 512
#define LROW  296          // feat LDS row stride in ushorts (592 B)

typedef short bf16x8 __attribute__((ext_vector_type(8)));  // 8 bf16 = 4 VGPRs
typedef float f32x4  __attribute__((ext_vector_type(4)));  // MFMA C/D

__device__ __forceinline__ unsigned short f2bf(float f) {
    unsigned int u = __float_as_uint(f);
    u += 0x7FFFu + ((u >> 16) & 1u);               // RNE
    return (unsigned short)(u >> 16);
}

// One block per output channel e. Computes the 245 length-64 dot products,
// cubic (Vandermonde) solve for the embedding select, packs the K=288 bf16
// coefficient row AcombT[e][k], and folds all constants into base[e].
__global__ __launch_bounds__(256) void precompute_kernel(
    const float* __restrict__ Wd, const float* __restrict__ bd,
    const float* __restrict__ Wc, const float* __restrict__ bc,
    const float* __restrict__ Wr, const float* __restrict__ br,
    const float* __restrict__ emb, const float* __restrict__ Wf,
    const float* __restrict__ bf,
    unsigned short* __restrict__ At, float* __restrict__ base)
{
    __shared__ float wfs[8960];
    __shared__ float dots[7][40];
    __shared__ float bds[3][40];
    const int e = blockIdx.x, t = threadIdx.x;

    const float4* src = (const float4*)(Wf + (size_t)e * 8960);
    float4* dst = (float4*)wfs;
    for (int idx = t; idx < 2240; idx += 256) dst[idx] = src[idx];
    __syncthreads();

    if (t < 245) {
        const int g = t / 35, i = t - 35 * g;
        const int gsel = (g < 3) ? g : 3;
        const float* wf = wfs + i * 256 + gsel * 64;
        const float* tab = (g == 0) ? (Wd + i * 64)
                         : (g == 1) ? (Wc + i * 64)
                         : (g == 2) ? (Wr + i * 64)
                         : (emb + ((size_t)i * 4 + (g - 3)) * 64);
        const float* btab = (g == 0) ? (bd + i * 64)
                          : (g == 1) ? (bc + i * 64) : (br + i * 64);
        // Unrolled so the 64 LDS + 64 global loads pipeline instead of
        // serializing on per-iteration waitcnts (was the latency bound).
        float dot = 0.f, bdot = 0.f;
        #pragma unroll 16
        for (int cc = 0; cc < 64; ++cc) {
            const int c = (cc + t) & 63;           // rotate start: LDS bank-spread
            const float wv = wf[c];
            dot = fmaf(tab[c], wv, dot);
            if (g < 3) bdot = fmaf(btab[c], wv, bdot);
        }
        dots[g][i] = dot;
        if (g < 3) bds[g][i] = bdot;
    }
    __syncthreads();

    if (t < ISLOT) {
        union { unsigned short h[8]; int4 v; } p;
        if (t < I_) {
            const float v0 = dots[3][t], v1 = dots[4][t], v2 = dots[5][t], v3 = dots[6][t];
            const float a = v1 - v0, b = v2 - v0, c = v3 - v0;
            const float k2 = 0.5f * (a + b);
            const float s  = 0.5f * (a - b);           // k1 + k3
            const float u  = 0.5f * (4.f * k2 - c);    // k1 + 4*k3
            const float k3 = (u - s) * (1.f / 3.f);
            const float k1 = s - k3;
            p.h[0] = f2bf(dots[0][t]); p.h[1] = f2bf(dots[1][t]); p.h[2] = f2bf(dots[2][t]);
            p.h[3] = f2bf(k1);         p.h[4] = f2bf(k2);         p.h[5] = f2bf(k3);
            p.h[6] = 0; p.h[7] = 0;
        } else {
            p.v = make_int4(0, 0, 0, 0);               // pad slot i=35
        }
        *(int4*)(At + (size_t)e * KP + t * 8) = p.v;
    }
    if (t < 64) {                                      // base[e] = bf + bias dots + sum k0
        float part = (t < I_) ? (bds[0][t] + bds[1][t] + bds[2][t] + dots[3][t]) : 0.f;
        #pragma unroll
        for (int mm = 1; mm < 64; mm <<= 1) part += __shfl_xor(part, mm, 64);
        if (t == 0) base[e] = bf[e] + part;
    }
}

// out(16384 x 256) = feat(16384 x 288) @ AcombT^T via 16x16x32 bf16 MFMA,
// fused bias + LayerNorm + ReLU. Block = 32 rows x all 256 channels, 4 waves.
__global__ __launch_bounds__(256) void main_kernel(
    const float* __restrict__ metadata,
    const unsigned short* __restrict__ At,
    const float* __restrict__ base,
    const float* __restrict__ gamma, const float* __restrict__ beta,
    float* __restrict__ out)
{
    __shared__ unsigned short feat[MROWS * LROW];
    __shared__ float redS[4][MROWS];
    __shared__ float redQ[4][MROWS];

    const int t  = threadIdx.x;
    const int b0 = blockIdx.x * MROWS;

    const int lane = t & 63, w = t >> 6;
    const int nlo = lane & 15, q = lane >> 4;

    // Hoist epilogue params so these loads fly under staging + MFMA.
    float baseN[4], gmN[4], btN[4];
    #pragma unroll
    for (int nn = 0; nn < 4; ++nn) {
        const int e = w * 64 + nn * 16 + nlo;
        baseN[nn] = base[e]; gmN[nn] = gamma[e]; btN[nn] = beta[e];
    }

    // Build bf16 feature rows [d,c,rl,x,x^2,x^3,0,0] per (row, i) directly from global.
    for (int cell = t; cell < MROWS * ISLOT; cell += 256) {
        const int r = cell / ISLOT, i = cell - r * ISLOT;
        union { unsigned short h[8]; int4 v; } p;
        if (i < I_) {
            const float* mp = metadata + (size_t)(b0 + r) * F_ + i;
            const float d = mp[0], c = mp[I_], rl = mp[2 * I_], x = mp[3 * I_];
            const float x2 = x * x, x3 = x2 * x;
            p.h[0] = f2bf(d);  p.h[1] = f2bf(c);  p.h[2] = f2bf(rl);
            p.h[3] = f2bf(x);  p.h[4] = f2bf(x2); p.h[5] = f2bf(x3);
            p.h[6] = 0; p.h[7] = 0;
        } else {
            p.v = make_int4(0, 0, 0, 0);
        }
        *(int4*)(feat + r * LROW + i * 8) = p.v;
    }
    __syncthreads();

    f32x4 acc[2][4];
    #pragma unroll
    for (int mt = 0; mt < 2; ++mt)
        #pragma unroll
        for (int nn = 0; nn < 4; ++nn) acc[mt][nn] = (f32x4){0.f, 0.f, 0.f, 0.f};

    // A-frag: lane holds feat[m = nlo][k = q*8 + j]; B-frag: At[e = nlo][k = q*8 + j]
    const unsigned short* ga = feat + nlo * LROW + q * 8;
    const unsigned short* gb = At + ((size_t)(w * 64 + nlo)) * KP + q * 8;

    #pragma unroll 3
    for (int ks = 0; ks < KP / 32; ++ks) {
        const bf16x8 a0 = *(const bf16x8*)(ga + ks * 32);
        const bf16x8 a1 = *(const bf16x8*)(ga + 16 * LROW + ks * 32);
        #pragma unroll
        for (int nn = 0; nn < 4; ++nn) {
            const bf16x8 b = *(const bf16x8*)(gb + (size_t)nn * 16 * KP + ks * 32);
            acc[0][nn] = __builtin_amdgcn_mfma_f32_16x16x32_bf16(a0, b, acc[0][nn], 0, 0, 0);
            acc[1][nn] = __builtin_amdgcn_mfma_f32_16x16x32_bf16(a1, b, acc[1][nn], 0, 0, 0);
        }
    }

    // Per-row moments: C/D layout row = q*4+reg (+16*mt), col = nlo (+16*nn).
    #pragma unroll
    for (int mt = 0; mt < 2; ++mt) {
        #pragma unroll
        for (int reg = 0; reg < 4; ++reg) {
            float s = 0.f, qq = 0.f;
            #pragma unroll
            for (int nn = 0; nn < 4; ++nn) {
                const float v = acc[mt][nn][reg] + baseN[nn];
                acc[mt][nn][reg] = v;
                s += v; qq += v * v;
            }
            #pragma unroll
            for (int mm = 1; mm < 16; mm <<= 1) {   // reduce over the 16 e-lanes
                s  += __shfl_xor(s, mm, 64);
                qq += __shfl_xor(qq, mm, 64);
            }
            if (nlo == 0) {
                const int row = mt * 16 + q * 4 + reg;
                redS[w][row] = s; redQ[w][row] = qq;
            }
        }
    }
    __syncthreads();

    #pragma unroll
    for (int mt = 0; mt < 2; ++mt) {
        #pragma unroll
        for (int reg = 0; reg < 4; ++reg) {
            const int row = mt * 16 + q * 4 + reg;
            const float S = redS[0][row] + redS[1][row] + redS[2][row] + redS[3][row];
            const float Q = redQ[0][row] + redQ[1][row] + redQ[2][row] + redQ[3][row];
            const float mu   = S * (1.f / E_);
            const float var  = Q * (1.f / E_) - mu * mu;
            const float rstd = rsqrtf(var + 1e-5f);
            float* orow = out + (size_t)(b0 + row) * E_ + w * 64 + nlo;
            #pragma unroll
            for (int nn = 0; nn < 4; ++nn) {
                const float v = (acc[mt][nn][reg] - mu) * rstd * gmN[nn] + btN[nn];
                orow[nn * 16] = fmaxf(v, 0.f);
            }
        }
    }
}

extern "C" void kernel_launch(void* const* d_in, const int* in_sizes, int n_in,
                              void* d_out, int out_size, void* d_ws, size_t ws_size,
                              hipStream_t stream) {
    const float* metadata = (const float*)d_in[0];
    const float* Wd  = (const float*)d_in[1];
    const float* bd  = (const float*)d_in[2];
    const float* Wc  = (const float*)d_in[3];
    const float* bc  = (const float*)d_in[4];
    const float* Wr  = (const float*)d_in[5];
    const float* br  = (const float*)d_in[6];
    const float* emb = (const float*)d_in[7];
    const float* Wf  = (const float*)d_in[8];
    const float* bf  = (const float*)d_in[9];
    const float* gamma = (const float*)d_in[10];
    const float* beta  = (const float*)d_in[11];

    unsigned short* At = (unsigned short*)d_ws;                    // 256*288*2 = 147456 B
    float* basep = (float*)((char*)d_ws + (size_t)E_ * KP * 2);    // 1 KB

    precompute_kernel<<<E_, 256, 0, stream>>>(Wd, bd, Wc, bc, Wr, br, emb, Wf, bf,
                                              At, basep);
    main_kernel<<<NBLK, 256, 0, stream>>>(metadata, At, basep, gamma, beta,
                                          (float*)d_out);
}